// Round 9
// baseline (29762.082 us; speedup 1.0000x reference)
//
#include <hip/hip_runtime.h>
#include <cstdint>
#include <math.h>

#define U 896
#define HU 448
#define TU 2688
#define TT 512
#define MM 80
#define CC 256
#define NTH 512
#define NW 28
#define NBLK 36

// ---------------- Threefry-2x32 (JAX partitionable) ----------------
__device__ __forceinline__ uint32_t rotl32(uint32_t v, int r){ return (v<<r)|(v>>(32-r)); }

__device__ void threefry(uint32_t k0, uint32_t k1, uint32_t x0, uint32_t x1,
                         uint32_t* o0, uint32_t* o1){
  uint32_t k2 = k0 ^ k1 ^ 0x1BD11BDAu;
  x0 += k0; x1 += k1;
  x0+=x1; x1=rotl32(x1,13); x1^=x0;
  x0+=x1; x1=rotl32(x1,15); x1^=x0;
  x0+=x1; x1=rotl32(x1,26); x1^=x0;
  x0+=x1; x1=rotl32(x1, 6); x1^=x0;
  x0+=k1; x1+=k2+1u;
  x0+=x1; x1=rotl32(x1,17); x1^=x0;
  x0+=x1; x1=rotl32(x1,29); x1^=x0;
  x0+=x1; x1=rotl32(x1,16); x1^=x0;
  x0+=x1; x1=rotl32(x1,24); x1^=x0;
  x0+=k2; x1+=k0+2u;
  x0+=x1; x1=rotl32(x1,13); x1^=x0;
  x0+=x1; x1=rotl32(x1,15); x1^=x0;
  x0+=x1; x1=rotl32(x1,26); x1^=x0;
  x0+=x1; x1=rotl32(x1, 6); x1^=x0;
  x0+=k0; x1+=k1+3u;
  x0+=x1; x1=rotl32(x1,17); x1^=x0;
  x0+=x1; x1=rotl32(x1,29); x1^=x0;
  x0+=x1; x1=rotl32(x1,16); x1^=x0;
  x0+=x1; x1=rotl32(x1,24); x1^=x0;
  x0+=k1; x1+=k2+4u;
  x0+=x1; x1=rotl32(x1,13); x1^=x0;
  x0+=x1; x1=rotl32(x1,15); x1^=x0;
  x0+=x1; x1=rotl32(x1,26); x1^=x0;
  x0+=x1; x1=rotl32(x1, 6); x1^=x0;
  x0+=k2; x1+=k0+5u;
  *o0 = x0; *o1 = x1;
}

__device__ float gumbel_from(uint32_t ka, uint32_t kb, uint32_t e){
  uint32_t o0, o1;
  threefry(ka, kb, 0u, e, &o0, &o1);
  uint32_t bits = o0 ^ o1;
  uint32_t m = bits >> 9;
  float u = (m == 0u) ? 1.17549435e-38f
                      : (__uint_as_float(m | 0x3f800000u) - 1.0f);
  float l1 = (float)log((double)u);
  float l2 = (float)log((double)(-l1));
  return -l2;
}

__device__ __forceinline__ float sig_f(float x){
  return (float)(0.5 + 0.5*tanh(0.5*(double)x));
}
__device__ __forceinline__ float tanh_f(float x){ return (float)tanh((double)x); }

// ---------------- coherent (agent-scope) access ----------------
__device__ __forceinline__ float gldf(const float* p){
  return __hip_atomic_load(p, __ATOMIC_RELAXED, __HIP_MEMORY_SCOPE_AGENT);
}
__device__ __forceinline__ void gstf(float* p, float v){
  __hip_atomic_store(p, v, __ATOMIC_RELAXED, __HIP_MEMORY_SCOPE_AGENT);
}
__device__ __forceinline__ float2 gldf2(const float* p){
  unsigned long long v = __hip_atomic_load((const unsigned long long*)p,
                                           __ATOMIC_RELAXED, __HIP_MEMORY_SCOPE_AGENT);
  union { unsigned long long u; float2 f; } cv; cv.u = v; return cv.f;
}
__device__ __forceinline__ void gstf2(float* p, float2 f){
  union { float2 f; unsigned long long u; } cv; cv.f = f;
  __hip_atomic_store((unsigned long long*)p, cv.u,
                     __ATOMIC_RELAXED, __HIP_MEMORY_SCOPE_AGENT);
}

// per-producer slots, 128B apart (32 u32); s_sleep poll (r5-best)
__device__ __forceinline__ void wait_slots(const uint32_t* slots, int n, uint32_t tgt, int tid){
  if (tid < n){
    const uint32_t* p = slots + (size_t)tid*32;
    int it = 0;
    while (__hip_atomic_load(p, __ATOMIC_RELAXED, __HIP_MEMORY_SCOPE_AGENT) < tgt){
      __builtin_amdgcn_s_sleep(1);
      if (++it > (1<<22)) break;
    }
  }
  __syncthreads();
}
__device__ __forceinline__ void publish_slot(uint32_t* slot, uint32_t v, int tid){
  __syncthreads();
  if (tid == 0)
    __hip_atomic_store(slot, v, __ATOMIC_RELEASE, __HIP_MEMORY_SCOPE_AGENT);
}

__device__ __forceinline__ void fma4(float4& a, const float4& w, float h){
  a.x += w.x*h; a.y += w.y*h; a.z += w.z*h; a.w += w.w*h;
}

// butterfly-sum 8 float4 accumulators over lane bits 3..5
__device__ __forceinline__ void bf8(float4* a){
  #pragma unroll
  for (int d=8; d<64; d<<=1){
    #pragma unroll
    for (int b=0;b<8;++b){
      a[b].x += __shfl_xor(a[b].x, d);
      a[b].y += __shfl_xor(a[b].y, d);
      a[b].z += __shfl_xor(a[b].z, d);
      a[b].w += __shfl_xor(a[b].w, d);
    }
  }
}

// tournament over 256 classes, 4/lane in one 64-lane wave (r8-proven)
__device__ __forceinline__ int sample256(float l0, float l1, float l2, float l3,
                                         const float g[4], int gl){
  float m = fmaxf(fmaxf(l0,l1), fmaxf(l2,l3));
  #pragma unroll
  for (int d=1; d<64; d<<=1) m = fmaxf(m, __shfl_xor(m, d));
  const float e0 = (float)exp((double)(l0-m));
  const float e1 = (float)exp((double)(l1-m));
  const float e2 = (float)exp((double)(l2-m));
  const float e3 = (float)exp((double)(l3-m));
  float ss = ((e0+e1)+(e2+e3));
  #pragma unroll
  for (int d=1; d<64; d<<=1) ss += __shfl_xor(ss, d);
  const float v0 = e0/ss + g[0], v1 = e1/ss + g[1];
  const float v2 = e2/ss + g[2], v3 = e3/ss + g[3];
  float v = v0; int bi = 4*gl;
  if (v1 > v){ v = v1; bi = 4*gl+1; }
  float vB = v2; int biB = 4*gl+2;
  if (v3 > vB){ vB = v3; biB = 4*gl+3; }
  if (vB > v || (vB == v && biB < bi)){ v = vB; bi = biB; }
  #pragma unroll
  for (int d=1; d<64; d<<=1){
    const float ov = __shfl_xor(v, d);
    const int   oi = __shfl_xor(bi, d);
    if (ov > v || (ov == v && oi < bi)){ v = ov; bi = oi; }
  }
  return bi;
}

// ---------------- K0: per-step keys ----------------
__global__ __launch_bounds__(256) void k_keys(uint32_t* __restrict__ kc, uint32_t* __restrict__ kf){
  int t = blockIdx.x*256 + threadIdx.x;
  if (t >= TT) return;
  uint32_t ka, kb;
  threefry(0u, 42u, 0u, (uint32_t)t, &ka, &kb);
  uint32_t c0,c1,f0,f1;
  threefry(ka, kb, 0u, 0u, &c0, &c1);
  threefry(ka, kb, 0u, 1u, &f0, &f1);
  kc[2*t] = c0; kc[2*t+1] = c1;
  kf[2*t] = f0; kf[2*t+1] = f1;
}

// ws offsets
#define O_SG    0
#define O_SH1   3584
#define O_KC    4608
#define O_KF    8704
#define O_NCV   12800
#define O_PRE   12928
#define O_IHB   98944
#define O_HGL   127616
#define WS_ZERO 156288

// ---------------- persistent kernel ----------------
__global__ __launch_bounds__(NTH, 2) void wavernn_persist(
    const float* __restrict__ mels, const float* __restrict__ Wk,
    const float* __restrict__ Wr,  const float* __restrict__ bias,
    const float* __restrict__ W1c, const float* __restrict__ b1c,
    const float* __restrict__ W2c, const float* __restrict__ b2c,
    const float* __restrict__ W1f, const float* __restrict__ b1f,
    const float* __restrict__ W2f, const float* __restrict__ b2f,
    float* __restrict__ out, char* __restrict__ ws)
{
  uint32_t* SG  = (uint32_t*)(ws + O_SG);
  uint32_t* SH1 = (uint32_t*)(ws + O_SH1);
  const uint32_t* kc = (const uint32_t*)(ws + O_KC);
  const uint32_t* kf = (const uint32_t*)(ws + O_KF);
  float* ncvB = (float*)(ws + O_NCV);   // [8]
  float* pre  = (float*)(ws + O_PRE);   // [8][2688]
  float* ihb  = (float*)(ws + O_IHB);   // [8][896]
  float* hgl  = (float*)(ws + O_HGL);   // [8][896]

  const int bk = blockIdx.x, tid = threadIdx.x;

  if (bk < NW){
    // ================= GEMM worker =================
    __shared__ __align__(16) float hlf[8*1024];
    __shared__ __align__(16) float wredf[8*288];
    const int ks = tid >> 3, k0 = ks*14;
    const int lane = tid & 63, wv = tid >> 6;
    const int U0 = bk*32;
    const int cb0 = U0 + (tid & 7)*4;
    const int xk = 896 + ks*2;
    const int r0 = ((xk   < 978) ? xk   : 978) - 896;
    const int r1 = ((xk+1 < 978) ? xk+1 : 978) - 896;

    for (int t=0; t<TT; ++t){
      wait_slots(SH1, 8, (uint32_t)t, tid);
      // stage h (float2 coherent)
      for (int i=tid;i<3584;i+=NTH){
        const int b = i/448, kp = (i - b*448)*2;
        const float2 h2 = gldf2(hgl + b*896 + kp);
        hlf[b*1024 + kp] = h2.x; hlf[b*1024 + kp + 1] = h2.y;
      }
      // stage x region (mel(t), cv = ncv(t-1), pad)
      for (int i=tid;i<1024;i+=NTH){
        const int b = i>>7, k2 = i&127;
        float v = 0.f;
        if (k2 < 80) v = mels[((size_t)b*TT + t)*MM + k2];
        else if (k2 == 80) v = gldf(ncvB + b);
        hlf[b*1024 + 896 + k2] = v;
      }
      __syncthreads();

      for (int g=0; g<3; ++g){
        const int cbg = g*896 + cb0;
        float4 aW[8], aX[8];
        #pragma unroll
        for (int b=0;b<8;++b){ aW[b]=make_float4(0,0,0,0); aX[b]=make_float4(0,0,0,0); }
        #pragma unroll 2
        for (int jj=0;jj<14;++jj){
          const float4 w = *(const float4*)(Wr + (size_t)(k0+jj)*TU + cbg);
          #pragma unroll
          for (int b=0;b<8;++b) fma4(aW[b], w, hlf[b*1024 + k0 + jj]);
        }
        {
          const float4 w0 = *(const float4*)(Wk + (size_t)r0*TU + cbg);
          const float4 w1 = *(const float4*)(Wk + (size_t)r1*TU + cbg);
          #pragma unroll
          for (int b=0;b<8;++b){
            fma4(aX[b], w0, hlf[b*1024 + 896 + ks*2]);
            fma4(aX[b], w1, hlf[b*1024 + 897 + ks*2]);
          }
        }
        if (g < 2){
          #pragma unroll
          for (int b=0;b<8;++b){
            aW[b].x += aX[b].x; aW[b].y += aX[b].y;
            aW[b].z += aX[b].z; aW[b].w += aX[b].w;
          }
          bf8(aW);
          if (lane < 8){
            float* dst = wredf + wv*288 + lane*36;
            #pragma unroll
            for (int b=0;b<8;++b) *(float4*)(dst + b*4) = aW[b];
          }
          __syncthreads();
          if (tid < 128){
            const int rb = tid>>4, rq = tid&15;
            float s0 = 0.f, s1 = 0.f;
            #pragma unroll
            for (int w=0; w<8; ++w){
              const float* wp = wredf + w*288 + (rq>>1)*36 + rb*4 + ((2*rq)&3);
              s0 += wp[0]; s1 += wp[1];
            }
            const int col0 = g*896 + U0 + 2*rq;
            gstf2(pre + rb*TU + col0,
                  make_float2(s0 + bias[col0]   + bias[TU + col0],
                              s1 + bias[col0+1] + bias[TU + col0+1]));
          }
          __syncthreads();
        } else {
          bf8(aW);
          if (lane < 8){
            float* dst = wredf + wv*288 + lane*36;
            #pragma unroll
            for (int b=0;b<8;++b) *(float4*)(dst + b*4) = aW[b];
          }
          __syncthreads();
          if (tid < 128){
            const int rb = tid>>4, rq = tid&15;
            float s0 = 0.f, s1 = 0.f;
            #pragma unroll
            for (int w=0; w<8; ++w){
              const float* wp = wredf + w*288 + (rq>>1)*36 + rb*4 + ((2*rq)&3);
              s0 += wp[0]; s1 += wp[1];
            }
            const int u0 = U0 + 2*rq;
            gstf2(ihb + rb*896 + u0,
                  make_float2(s0 + bias[TU + 1792 + u0],
                              s1 + bias[TU + 1792 + u0 + 1]));
          }
          __syncthreads();
          bf8(aX);
          if (lane < 8){
            float* dst = wredf + wv*288 + lane*36;
            #pragma unroll
            for (int b=0;b<8;++b) *(float4*)(dst + b*4) = aX[b];
          }
          __syncthreads();
          if (tid < 128){
            const int rb = tid>>4, rq = tid&15;
            float s0 = 0.f, s1 = 0.f;
            #pragma unroll
            for (int w=0; w<8; ++w){
              const float* wp = wredf + w*288 + (rq>>1)*36 + rb*4 + ((2*rq)&3);
              s0 += wp[0]; s1 += wp[1];
            }
            const int u0 = U0 + 2*rq;
            gstf2(pre + rb*TU + 1792 + u0,
                  make_float2(s0 + bias[1792 + u0],
                              s1 + bias[1792 + u0 + 1]));
          }
          __syncthreads();
        }
      }
      publish_slot(SG + bk*32, (uint32_t)(t+1), tid);
    }
  } else {
    // ================= per-batch sampler block (b = bk-NW) =================
    const int b = bk - NW;
    __shared__ __align__(16) float hstate[896];   // h carried across steps (LDS)
    __shared__ __align__(16) float h0s[448];
    __shared__ __align__(16) float h1hi[448];
    __shared__ __align__(16) float y1[448];
    __shared__ __align__(16) float lg[256];
    __shared__ float fvS;
    __shared__ int   ncSh;

    for (int i=tid;i<896;i+=NTH) hstate[i] = 0.f;
    if (tid==0) fvS = 0.f;
    __syncthreads();

    const int u = tid;            // gate index (tid<448)
    for (int t=0; t<TT; ++t){
      // gumbels precomputed before the wait (off critical path)
      float gc[4], gf[4];
      if (tid < 64){
        const uint32_t ca = kc[2*t], cb2 = kc[2*t+1];
        const uint32_t fa = kf[2*t], fb2 = kf[2*t+1];
        #pragma unroll
        for (int i=0;i<4;++i){
          gc[i] = gumbel_from(ca, cb2, (uint32_t)(b*CC + 4*tid + i));
          gf[i] = gumbel_from(fa, fb2, (uint32_t)(b*CC + 4*tid + i));
        }
      }
      wait_slots(SG, NW, (uint32_t)(t+1), tid);
      const float fv = fvS;

      // ---- coarse gates (u < 448) ----
      float azc=0.f, arc=0.f, axc=0.f, ihc=0.f;
      if (tid < 448){
        azc = gldf(pre + b*TU + u)        + fv*Wk[(size_t)81*TU + u];
        arc = gldf(pre + b*TU + 896 + u)  + fv*Wk[(size_t)81*TU + 896 + u];
        axc = gldf(pre + b*TU + 1792 + u) + fv*Wk[(size_t)81*TU + 1792 + u];
        ihc = gldf(ihb + b*896 + u);
        const float z = sig_f(azc), r = sig_f(arc);
        const float hh = tanh_f(axc + r*ihc);
        h0s[u] = z*hstate[u] + (1.0f - z)*hh;
      }
      __syncthreads();

      // ---- y1c = relu(h0 @ W1c + b1c) ----
      if (tid < 448){
        float s0=0.f,s1=0.f,s2=0.f,s3=0.f;
        #pragma unroll 4
        for (int i=0;i<448;i+=4){
          s0 += h0s[i]  *W1c[(size_t)(i)  *HU + tid];
          s1 += h0s[i+1]*W1c[(size_t)(i+1)*HU + tid];
          s2 += h0s[i+2]*W1c[(size_t)(i+2)*HU + tid];
          s3 += h0s[i+3]*W1c[(size_t)(i+3)*HU + tid];
        }
        y1[tid] = fmaxf(((s0+s1)+(s2+s3)) + b1c[tid], 0.0f);
      }
      __syncthreads();

      // ---- lgtC = y1 @ W2c + b2c ----
      if (tid < 256){
        float s0=0.f,s1=0.f,s2=0.f,s3=0.f;
        #pragma unroll 4
        for (int i=0;i<448;i+=4){
          s0 += y1[i]  *W2c[(size_t)(i)  *CC + tid];
          s1 += y1[i+1]*W2c[(size_t)(i+1)*CC + tid];
          s2 += y1[i+2]*W2c[(size_t)(i+2)*CC + tid];
          s3 += y1[i+3]*W2c[(size_t)(i+3)*CC + tid];
        }
        lg[tid] = ((s0+s1)+(s2+s3)) + b2c[tid];
      }
      __syncthreads();

      // ---- sample_c (wave 0) ----
      if (tid < 64){
        const int nc = sample256(lg[4*tid], lg[4*tid+1], lg[4*tid+2], lg[4*tid+3], gc, tid);
        if (tid == 0){
          ncSh = nc;
          gstf(ncvB + b, (float)nc/255.0f*2.0f - 1.0f);
        }
      }
      __syncthreads();
      const float ncv = (float)ncSh/255.0f*2.0f - 1.0f;

      // ---- fine gates (u and u+448) -> hstate, h1hi ----
      if (tid < 448){
        {
          const float az = azc + ncv*Wk[(size_t)82*TU + u];
          const float ar = arc + ncv*Wk[(size_t)82*TU + 896 + u];
          const float ax = axc + ncv*Wk[(size_t)82*TU + 1792 + u];
          const float z = sig_f(az), r = sig_f(ar);
          const float hh = tanh_f(ax + r*ihc);
          hstate[u] = z*hstate[u] + (1.0f - z)*hh;
        }
        {
          const int u2 = u + 448;
          const float az = gldf(pre + b*TU + u2)        + fv*Wk[(size_t)81*TU + u2]        + ncv*Wk[(size_t)82*TU + u2];
          const float ar = gldf(pre + b*TU + 896 + u2)  + fv*Wk[(size_t)81*TU + 896 + u2]  + ncv*Wk[(size_t)82*TU + 896 + u2];
          const float ax = gldf(pre + b*TU + 1792 + u2) + fv*Wk[(size_t)81*TU + 1792 + u2] + ncv*Wk[(size_t)82*TU + 1792 + u2];
          const float ih = gldf(ihb + b*896 + u2);
          const float z = sig_f(az), r = sig_f(ar);
          const float hh = tanh_f(ax + r*ih);
          const float hn = z*hstate[u2] + (1.0f - z)*hh;
          hstate[u2] = hn;
          h1hi[u] = hn;
        }
      }
      __syncthreads();
      // publish h1 (float2)
      for (int i=tid;i<448;i+=NTH)
        gstf2(hgl + b*896 + 2*i, make_float2(hstate[2*i], hstate[2*i+1]));
      publish_slot(SH1 + b*32, (uint32_t)(t+1), tid);

      // ---- fine head (overlaps next GEMM) ----
      if (tid < 448){
        float s0=0.f,s1=0.f,s2=0.f,s3=0.f;
        #pragma unroll 4
        for (int i=0;i<448;i+=4){
          s0 += h1hi[i]  *W1f[(size_t)(i)  *HU + tid];
          s1 += h1hi[i+1]*W1f[(size_t)(i+1)*HU + tid];
          s2 += h1hi[i+2]*W1f[(size_t)(i+2)*HU + tid];
          s3 += h1hi[i+3]*W1f[(size_t)(i+3)*HU + tid];
        }
        y1[tid] = fmaxf(((s0+s1)+(s2+s3)) + b1f[tid], 0.0f);
      }
      __syncthreads();
      if (tid < 256){
        float s0=0.f,s1=0.f,s2=0.f,s3=0.f;
        #pragma unroll 4
        for (int i=0;i<448;i+=4){
          s0 += y1[i]  *W2f[(size_t)(i)  *CC + tid];
          s1 += y1[i+1]*W2f[(size_t)(i+1)*CC + tid];
          s2 += y1[i+2]*W2f[(size_t)(i+2)*CC + tid];
          s3 += y1[i+3]*W2f[(size_t)(i+3)*CC + tid];
        }
        lg[tid] = ((s0+s1)+(s2+s3)) + b2f[tid];
      }
      __syncthreads();
      if (tid < 64){
        const int nf = sample256(lg[4*tid], lg[4*tid+1], lg[4*tid+2], lg[4*tid+3], gf, tid);
        if (tid == 0){
          fvS = (float)nf/255.0f*2.0f - 1.0f;
          out[(size_t)b*TT + t] = ((float)ncSh*256.0f + (float)nf)/32767.5f - 1.0f;
        }
      }
      __syncthreads();
    }
  }
}

extern "C" void kernel_launch(void* const* d_in, const int* in_sizes, int n_in,
                              void* d_out, int out_size, void* d_ws, size_t ws_size,
                              hipStream_t stream) {
  const float* mels = (const float*)d_in[0];
  const float* Wk   = (const float*)d_in[1];
  const float* Wr   = (const float*)d_in[2];
  const float* bias = (const float*)d_in[3];
  const float* W1c  = (const float*)d_in[4];
  const float* b1c  = (const float*)d_in[5];
  const float* W2c  = (const float*)d_in[6];
  const float* b2c  = (const float*)d_in[7];
  const float* W1f  = (const float*)d_in[8];
  const float* b1f  = (const float*)d_in[9];
  const float* W2f  = (const float*)d_in[10];
  const float* b2f  = (const float*)d_in[11];
  float* out = (float*)d_out;
  char* wsb = (char*)d_ws;

  uint32_t* kc = (uint32_t*)(wsb + O_KC);
  uint32_t* kf = (uint32_t*)(wsb + O_KF);

  hipMemsetAsync(d_ws, 0, WS_ZERO, stream);
  k_keys<<<2,256,0,stream>>>(kc, kf);

  void* args[] = { (void*)&mels, (void*)&Wk, (void*)&Wr, (void*)&bias,
                   (void*)&W1c, (void*)&b1c, (void*)&W2c, (void*)&b2c,
                   (void*)&W1f, (void*)&b1f, (void*)&W2f, (void*)&b2f,
                   (void*)&out, (void*)&wsb };
  hipLaunchCooperativeKernel((const void*)wavernn_persist, dim3(NBLK), dim3(NTH),
                             args, 0, stream);
}